// Round 6
// baseline (7460.972 us; speedup 1.0000x reference)
//
#include <hip/hip_runtime.h>
#include <math.h>

#define N_NODES 100000
#define N_EV    50000
#define NF4     25000   // N_NODES/4
#define CAP     1024    // candidate list capacity per community
#define NLAD    32
#define LAD_T0  (-0.25f)
#define LAD_W   (0.03125f)   // 1/32

typedef __attribute__((ext_vector_type(8))) short short8;
typedef __attribute__((ext_vector_type(4))) float f32x4;

static __device__ __forceinline__ short f2bf(float f) {
    union { float f; unsigned u; } v; v.f = f;
    unsigned r = (v.u + 0x7FFFu + ((v.u >> 16) & 1u)) >> 16;
    return (short)r;
}
static __device__ __forceinline__ float bf2f(short h) {
    union { unsigned u; float f; } v; v.u = ((unsigned)(unsigned short)h) << 16;
    return v.f;
}

// ---------------- build GRU weight matrix in MFMA-fragment order (bf16) ----------------
__global__ void k_build(const float* __restrict__ W_ih, const float* __restrict__ b_ih,
                        const float* __restrict__ W_hh, const float* __restrict__ b_hh,
                        short* __restrict__ Wbf, float* __restrict__ bcat) {
    int idx = blockIdx.x * 256 + threadIdx.x;   // 512*512 = 262144
    int j = idx & 7, lane = (idx >> 3) & 63, sub = idx >> 9;
    int ks = sub & 15, NB = sub >> 4;
    int k = ks * 32 + ((lane >> 4) & 3) * 8 + j;
    int o = NB * 16 + (lane & 15);
    int g = o >> 7, d = o & 127;
    float v;
    if (g == 0)      v = W_ih[d * 512 + k] + (k < 128 ? W_hh[d * 128 + k] : 0.f);
    else if (g == 1) v = W_ih[(128 + d) * 512 + k] + (k < 128 ? W_hh[(128 + d) * 128 + k] : 0.f);
    else if (g == 2) v = W_ih[(256 + d) * 512 + k];
    else             v = (k < 128 ? W_hh[(256 + d) * 128 + k] : 0.f);
    Wbf[idx] = f2bf(v);
    if (idx < 512) {
        int gg = idx >> 7, dd = idx & 127;
        float b;
        if (gg == 0)      b = b_ih[dd] + b_hh[dd];
        else if (gg == 1) b = b_ih[128 + dd] + b_hh[128 + dd];
        else if (gg == 2) b = b_ih[256 + dd];
        else              b = b_hh[256 + dd];
        bcat[idx] = b;
    }
}

// ---------------- normalize centroids + pack hi/lo A-fragments ----------------
__global__ void k_cen(const float* __restrict__ centroids,
                      short* __restrict__ cenf_hi, short* __restrict__ cenf_lo) {
    int c = blockIdx.x, t = threadIdx.x;  // 128 threads
    float v = centroids[c * 128 + t];
    float ss = v * v;
    #pragma unroll
    for (int m = 1; m < 64; m <<= 1) ss += __shfl_xor(ss, m);
    __shared__ float tmp[2];
    if ((t & 63) == 0) tmp[t >> 6] = ss;
    __syncthreads();
    float tot = tmp[0] + tmp[1];
    float nv = v / (sqrtf(tot) + 1e-8f);
    short hi = f2bf(nv);
    short lo = f2bf(nv - bf2f(hi));
    int ct = c >> 4, c_l = c & 15, kstep = t >> 5, kj = t & 31;
    int lane = c_l + 16 * (kj >> 3), j = kj & 7;
    int fidx = ((ct * 4 + kstep) * 64 + lane) * 8 + j;
    cenf_hi[fidx] = hi;
    cenf_lo[fidx] = lo;
}

// ---------------- pack proj_W hi/lo B-fragments ----------------
__global__ void k_packW(const float* __restrict__ proj_W,
                        short* __restrict__ pw_hi, short* __restrict__ pw_lo) {
    int idx = blockIdx.x * 256 + threadIdx.x;   // 16384
    int k = idx >> 7, p = idx & 127;
    float v = proj_W[k * 128 + p];
    short hi = f2bf(v);
    short lo = f2bf(v - bf2f(hi));
    int pt = p >> 4, p_l = p & 15, kstep = k >> 5, kj = k & 31;
    int lane = p_l + 16 * (kj >> 3), j = kj & 7;
    int fidx = ((pt * 4 + kstep) * 64 + lane) * 8 + j;
    pw_hi[fidx] = hi;
    pw_lo[fidx] = lo;
}

// ---------------- event scatter ----------------
__global__ __launch_bounds__(256) void k_scatter(
        const float* __restrict__ node_memory, const float* __restrict__ last_update,
        const float* __restrict__ event_feat, const float* __restrict__ t_arr,
        const int* __restrict__ src, const int* __restrict__ dst,
        const float* __restrict__ time_w, const float* __restrict__ time_b,
        float* __restrict__ S, float* __restrict__ cnt) {
    int e = blockIdx.x * 4 + (threadIdx.x >> 6);   // one wave per event, e in [0, 2E)
    int l = threadIdx.x & 63;
    int eb  = e < N_EV ? e : e - N_EV;
    int idx = e < N_EV ? src[e] : dst[eb];
    int oth = e < N_EV ? dst[e] : src[eb];
    float tt = t_arr[eb];
    float dt = tt - last_update[idx];
    float* Sd = S + (size_t)idx * 384;
    const float* om = node_memory + (size_t)oth * 128;
    const float* ef = event_feat + (size_t)eb * 128;
    #pragma unroll
    for (int h = 0; h < 2; h++) {
        int d = l + h * 64;
        atomicAdd(&Sd[d], om[d]);
        atomicAdd(&Sd[128 + d], ef[d]);
        atomicAdd(&Sd[256 + d], cosf(fmaf(dt, time_w[d], time_b[d])));
    }
    if (l == 0) atomicAdd(&cnt[idx], 1.0f);
}

// ---------------- fused GRU via MFMA bf16 (32 nodes/block, 512 threads, 8 waves) ----------------
__global__ __launch_bounds__(512, 4) void k_gru(
        const float* __restrict__ node_memory, const float* __restrict__ S,
        const float* __restrict__ cnt, const short* __restrict__ Wbf,
        const float* __restrict__ bcat, float* __restrict__ new_mem) {
    __shared__ __align__(16) char ldsraw[65536];
    short* Ab  = (short*)ldsraw;          // 32 KiB: 32 nodes x 512 k bf16 (frag order)
    float* epi = (float*)ldsraw;          // 64 KiB: [4 gates][32 rows][128 d] (after K-loop)
    int t = threadIdx.x;
    int n0 = blockIdx.x * 32;

    #pragma unroll
    for (int pass = 0; pass < 4; pass++) {
        int m = t >> 4;                       // 0..31
        int k0 = (t & 15) * 8 + pass * 128;   // 0..504
        float vals[8];
        if (pass == 0) {
            const float4* p = (const float4*)&node_memory[(size_t)(n0 + m) * 128 + k0];
            float4 x = p[0], y = p[1];
            vals[0]=x.x; vals[1]=x.y; vals[2]=x.z; vals[3]=x.w;
            vals[4]=y.x; vals[5]=y.y; vals[6]=y.z; vals[7]=y.w;
        } else {
            float inv = 1.f / fmaxf(cnt[n0 + m], 1.f);
            const float4* p = (const float4*)&S[(size_t)(n0 + m) * 384 + (k0 - 128)];
            float4 x = p[0], y = p[1];
            vals[0]=x.x*inv; vals[1]=x.y*inv; vals[2]=x.z*inv; vals[3]=x.w*inv;
            vals[4]=y.x*inv; vals[5]=y.y*inv; vals[6]=y.z*inv; vals[7]=y.w*inv;
        }
        int mb = m >> 4, ks = k0 >> 5;
        int lane = ((k0 >> 3) & 3) * 16 + (m & 15);
        int g = (mb * 16 + ks) * 64 + lane;
        g ^= ((g >> 4) & 7);
        short8 sv;
        #pragma unroll
        for (int j = 0; j < 8; j++) sv[j] = f2bf(vals[j]);
        *(short8*)&Ab[g * 8] = sv;
    }
    __syncthreads();

    int w = t >> 6, l = t & 63;
    int cg = w & 3, kh = w >> 2;
    f32x4 acc[2][8];
    #pragma unroll
    for (int mb = 0; mb < 2; mb++)
        #pragma unroll
        for (int nb = 0; nb < 8; nb++) acc[mb][nb] = (f32x4){0.f, 0.f, 0.f, 0.f};

    const short8* Bp = (const short8*)Wbf;
    #pragma unroll 2
    for (int kk = 0; kk < 8; kk++) {
        int ks = kh * 8 + kk;
        short8 bfr[8];
        #pragma unroll
        for (int nb = 0; nb < 8; nb++)
            bfr[nb] = Bp[(((cg * 8 + nb) * 16 + ks) * 64) + l];
        short8 afr[2];
        #pragma unroll
        for (int mb = 0; mb < 2; mb++) {
            int g = (mb * 16 + ks) * 64 + l;
            g ^= ((g >> 4) & 7);
            afr[mb] = *(const short8*)&Ab[g * 8];
        }
        #pragma unroll
        for (int mb = 0; mb < 2; mb++)
            #pragma unroll
            for (int nb = 0; nb < 8; nb++)
                acc[mb][nb] = __builtin_amdgcn_mfma_f32_16x16x32_bf16(
                    afr[mb], bfr[nb], acc[mb][nb], 0, 0, 0);
    }
    __syncthreads();   // A dead -> epi reuse

    if (kh == 0) {
        #pragma unroll
        for (int mb = 0; mb < 2; mb++)
            #pragma unroll
            for (int nb = 0; nb < 8; nb++)
                #pragma unroll
                for (int r = 0; r < 4; r++) {
                    int row = mb * 16 + (l >> 4) * 4 + r;
                    int d = nb * 16 + (l & 15);
                    epi[(cg * 32 + row) * 128 + d] = acc[mb][nb][r];
                }
    }
    __syncthreads();
    if (kh == 1) {
        #pragma unroll
        for (int mb = 0; mb < 2; mb++)
            #pragma unroll
            for (int nb = 0; nb < 8; nb++)
                #pragma unroll
                for (int r = 0; r < 4; r++) {
                    int row = mb * 16 + (l >> 4) * 4 + r;
                    int d = nb * 16 + (l & 15);
                    epi[(cg * 32 + row) * 128 + d] += acc[mb][nb][r];
                }
    }
    __syncthreads();

    int d = t & 127;
    float br = bcat[d], bz = bcat[128 + d], bn = bcat[256 + d], bh = bcat[384 + d];
    #pragma unroll
    for (int i = 0; i < 8; i++) {
        int row = (t >> 7) * 8 + i;
        int n = n0 + row;
        float c = cnt[n];
        float h = node_memory[(size_t)n * 128 + d];
        float rs = epi[(0 * 32 + row) * 128 + d] + br;
        float zs = epi[(1 * 32 + row) * 128 + d] + bz;
        float gn = epi[(2 * 32 + row) * 128 + d] + bn;
        float gh = epi[(3 * 32 + row) * 128 + d] + bh;
        float r_ = 1.f / (1.f + expf(-rs));
        float z_ = 1.f / (1.f + expf(-zs));
        float nn = tanhf(gn + r_ * gh);
        float nm = (1.f - z_) * nn + z_ * h;
        new_mem[(size_t)n * 128 + d] = (c > 0.f) ? nm : h;
    }
}

// ---------------- k_sim: feat -> proj -> normalize -> sim via split-bf16 MFMA ----------------
__global__ __launch_bounds__(256, 2) void k_sim(
        const float* __restrict__ new_mem, const float* __restrict__ node_features,
        const short* __restrict__ pw_hi, const short* __restrict__ pw_lo,
        const float* __restrict__ proj_b,
        const short* __restrict__ cenf_hi, const short* __restrict__ cenf_lo,
        float* __restrict__ simT) {
    __shared__ __align__(16) float feat[64 * 128];   // 32 KB, XOR-swizzled 16B granules
    __shared__ __align__(16) short pfh[64 * 128];    // 16 KB
    __shared__ __align__(16) short pfl[64 * 128];    // 16 KB
    int t = threadIdx.x;
    int n0 = blockIdx.x * 64;

    #pragma unroll
    for (int r = 0; r < 8; r++) {
        int idx = r * 256 + t;            // granule 0..2047
        int node = idx >> 5, gk = idx & 31;
        float4 v = make_float4(0.f, 0.f, 0.f, 0.f);
        int n = n0 + node;
        if (n < N_NODES) {
            float4 a = *(const float4*)&new_mem[(size_t)n * 128 + gk * 4];
            float4 b = *(const float4*)&node_features[(size_t)n * 128 + gk * 4];
            v = make_float4(a.x + b.x, a.y + b.y, a.z + b.z, a.w + b.w);
        }
        int gs = gk ^ (node & 7);
        *(float4*)&feat[(node * 32 + gs) * 4] = v;
    }
    __syncthreads();

    int w = t >> 6, l = t & 63;
    int lm = l & 15, lk = l >> 4;

    f32x4 pacc[8];
    #pragma unroll
    for (int nb = 0; nb < 8; nb++) pacc[nb] = (f32x4){0.f, 0.f, 0.f, 0.f};
    #pragma unroll
    for (int ks = 0; ks < 4; ks++) {
        int node = w * 16 + lm;
        int gk0 = ks * 8 + lk * 2;
        float4 a0 = *(const float4*)&feat[(node * 32 + (gk0 ^ (node & 7))) * 4];
        float4 a1 = *(const float4*)&feat[(node * 32 + ((gk0 + 1) ^ (node & 7))) * 4];
        float av[8] = {a0.x, a0.y, a0.z, a0.w, a1.x, a1.y, a1.z, a1.w};
        short8 Ah, Al;
        #pragma unroll
        for (int j = 0; j < 8; j++) {
            short h = f2bf(av[j]);
            Ah[j] = h;
            Al[j] = f2bf(av[j] - bf2f(h));
        }
        #pragma unroll
        for (int nb = 0; nb < 8; nb++) {
            int fidx = ((nb * 4 + ks) * 64 + l) * 8;
            short8 Bh = *(const short8*)&pw_hi[fidx];
            short8 Bl = *(const short8*)&pw_lo[fidx];
            pacc[nb] = __builtin_amdgcn_mfma_f32_16x16x32_bf16(Ah, Bh, pacc[nb], 0, 0, 0);
            pacc[nb] = __builtin_amdgcn_mfma_f32_16x16x32_bf16(Ah, Bl, pacc[nb], 0, 0, 0);
            pacc[nb] = __builtin_amdgcn_mfma_f32_16x16x32_bf16(Al, Bh, pacc[nb], 0, 0, 0);
        }
    }
    float ssq[4] = {0.f, 0.f, 0.f, 0.f};
    #pragma unroll
    for (int nb = 0; nb < 8; nb++) {
        float pb = proj_b[nb * 16 + lm];
        #pragma unroll
        for (int r = 0; r < 4; r++) {
            pacc[nb][r] += pb;
            ssq[r] = fmaf(pacc[nb][r], pacc[nb][r], ssq[r]);
        }
    }
    #pragma unroll
    for (int m = 1; m < 16; m <<= 1)
        #pragma unroll
        for (int r = 0; r < 4; r++) ssq[r] += __shfl_xor(ssq[r], m);
    float inv[4];
    #pragma unroll
    for (int r = 0; r < 4; r++) inv[r] = 1.f / (sqrtf(ssq[r]) + 1e-8f);
    #pragma unroll
    for (int nb = 0; nb < 8; nb++)
        #pragma unroll
        for (int r = 0; r < 4; r++) {
            float v = pacc[nb][r] * inv[r];
            short h = f2bf(v);
            short lo2 = f2bf(v - bf2f(h));
            int node = w * 16 + lk * 4 + r;
            int p = nb * 16 + lm;
            int g = node * 16 + (((p >> 3)) ^ (node & 7));
            int si = g * 8 + (p & 7);
            pfh[si] = h;
            pfl[si] = lo2;
        }
    __syncthreads();

    f32x4 sacc[4][4];
    #pragma unroll
    for (int ct = 0; ct < 4; ct++)
        #pragma unroll
        for (int mt = 0; mt < 4; mt++) sacc[ct][mt] = (f32x4){0.f, 0.f, 0.f, 0.f};
    #pragma unroll
    for (int ks = 0; ks < 4; ks++) {
        short8 Bh[4], Bl[4];
        #pragma unroll
        for (int mt = 0; mt < 4; mt++) {
            int node = mt * 16 + lm;
            int g = node * 16 + ((ks * 4 + lk) ^ (node & 7));
            Bh[mt] = *(const short8*)&pfh[g * 8];
            Bl[mt] = *(const short8*)&pfl[g * 8];
        }
        #pragma unroll
        for (int ct = 0; ct < 4; ct++) {
            int ctg = w * 4 + ct;
            int fidx = ((ctg * 4 + ks) * 64 + l) * 8;
            short8 Ah = *(const short8*)&cenf_hi[fidx];
            short8 Al = *(const short8*)&cenf_lo[fidx];
            #pragma unroll
            for (int mt = 0; mt < 4; mt++) {
                sacc[ct][mt] = __builtin_amdgcn_mfma_f32_16x16x32_bf16(Ah, Bh[mt], sacc[ct][mt], 0, 0, 0);
                sacc[ct][mt] = __builtin_amdgcn_mfma_f32_16x16x32_bf16(Ah, Bl[mt], sacc[ct][mt], 0, 0, 0);
                sacc[ct][mt] = __builtin_amdgcn_mfma_f32_16x16x32_bf16(Al, Bh[mt], sacc[ct][mt], 0, 0, 0);
            }
        }
    }
    #pragma unroll
    for (int ct = 0; ct < 4; ct++) {
        int cbase = (w * 4 + ct) * 16 + lk * 4;
        #pragma unroll
        for (int r = 0; r < 4; r++) {
            size_t rowoff = (size_t)(cbase + r) * N_NODES;
            #pragma unroll
            for (int mt = 0; mt < 4; mt++) {
                int n = n0 + mt * 16 + lm;
                if (n < N_NODES) simT[rowoff + n] = sacc[ct][mt][r];
            }
        }
    }
}

// ---------------- pass A: atomic-free comparison ladder (suffix counts + total sum) ----------------
__global__ __launch_bounds__(256) void k_hist(const float* __restrict__ simT,
                                              float* __restrict__ gcnt) {
    int cid = blockIdx.x >> 2, slice = blockIdx.x & 3;
    int t = threadIdx.x;
    const float4* z4 = (const float4*)(simT + (size_t)cid * N_NODES);
    int cnt[NLAD];
    #pragma unroll
    for (int j = 0; j < NLAD; j++) cnt[j] = 0;
    float stot = 0.f;
    int end = slice * 6250 + 6250;
    for (int i = slice * 6250 + t; i < end; i += 256) {
        float4 a = z4[i];
        stot += (a.x + a.y) + (a.z + a.w);
        #pragma unroll
        for (int j = 0; j < NLAD; j++) {
            float T = LAD_T0 + j * LAD_W;
            cnt[j] += (int)(a.x > T) + (int)(a.y > T) + (int)(a.z > T) + (int)(a.w > T);
        }
    }
    #pragma unroll
    for (int m = 1; m < 64; m <<= 1) {
        #pragma unroll
        for (int j = 0; j < NLAD; j++) cnt[j] += __shfl_xor(cnt[j], m);
        stot += __shfl_xor(stot, m);
    }
    __shared__ float red[4][NLAD + 1];
    int w = t >> 6;
    if ((t & 63) == 0) {
        #pragma unroll
        for (int j = 0; j < NLAD; j++) red[w][j] = (float)cnt[j];
        red[w][NLAD] = stot;
    }
    __syncthreads();
    if (t < NLAD + 1) {
        float s = red[0][t] + red[1][t] + red[2][t] + red[3][t];
        atomicAdd(&gcnt[cid * (NLAD + 1) + t], s);
    }
}

// ---------------- pass B: binned Michelot on ladder suffix counts -> thresh <= tau* ----------------
// Uses bin-edge lower-bound suffix sums: underestimating S keeps every iterate <= tau*.
__global__ void k_tau0(const float* __restrict__ gcnt, float* __restrict__ thresh) {
    __shared__ float Slo[NLAD][256];
    __shared__ float Klds[NLAD][256];
    int c = threadIdx.x;   // 256 threads, 1 block
    const float* K = gcnt + c * (NLAD + 1);
    float Stot = K[NLAD];
    float acc = 0.f, Kb1 = 0.f;
    for (int b = NLAD - 1; b >= 0; b--) {
        float Kb = K[b];
        acc += (Kb - Kb1) * (LAD_T0 + b * LAD_W);
        Slo[b][c] = acc;
        Klds[b][c] = Kb;
        Kb1 = Kb;
    }
    float tau = (Stot - 1.f) / (float)N_NODES;
    float best = tau;
    int jprev = -1;
    for (int it = 0; it < 40; it++) {
        int j = (int)floorf((tau - LAD_T0) * 32.0f);
        if (j > NLAD - 1) j = NLAD - 1;
        if (j < 0 || j == jprev) break;
        jprev = j;
        float Kj = Klds[j][c];
        if (Kj < 0.5f) break;
        float tn = (Slo[j][c] - 1.f) / Kj;
        if (tn > best) best = tn;
        if (tn > tau) tau = tn; else break;
    }
    thresh[c] = best - 1e-5f;
}

// ---------------- pass C: gather candidates z > thresh ----------------
__global__ __launch_bounds__(256) void k_gather(const float* __restrict__ simT,
                                                const float* __restrict__ thresh,
                                                int* __restrict__ ccount,
                                                float2* __restrict__ clist) {
    int cid = blockIdx.x >> 2, slice = blockIdx.x & 3;
    float th = thresh[cid];
    const float4* z4 = (const float4*)(simT + (size_t)cid * N_NODES);
    int t = threadIdx.x;
    int end = slice * 6250 + 6250;
    for (int i = slice * 6250 + t; i < end; i += 256) {
        float4 a = z4[i];
        int nb = i * 4;
        #define GATH(v, j) if ((v) > th) { int p = atomicAdd(&ccount[cid], 1); \
            if (p < CAP) clist[(size_t)cid * CAP + p] = make_float2((v), __int_as_float(nb + (j))); }
        GATH(a.x, 0) GATH(a.y, 1) GATH(a.z, 2) GATH(a.w, 3)
        #undef GATH
    }
}

// ---------------- pass D: exact Michelot on candidates + c_mem accumulation ----------------
__global__ __launch_bounds__(256) void k_csolve(
        const float* __restrict__ simT, const float* __restrict__ new_mem,
        const int* __restrict__ ccount, const float2* __restrict__ clist,
        float* __restrict__ c_mem) {
    int c = blockIdx.x, t = threadIdx.x;  // 256 threads
    __shared__ float zv[CAP];
    __shared__ int   zn[CAP];
    __shared__ float redS[4], redK[4], part[256];
    int raw = ccount[c];
    if (raw == 0) {
        if (t < 128) c_mem[c * 128 + t] = 0.f;
        return;
    }
    float tau;
    if (raw <= CAP) {
        int cnt = raw;
        for (int i = t; i < cnt; i += 256) {
            float2 e = clist[(size_t)c * CAP + i];
            zv[i] = e.x; zn[i] = __float_as_int(e.y);
        }
        __syncthreads();
        float ls = 0.f;
        for (int i = t; i < cnt; i += 256) ls += zv[i];
        #pragma unroll
        for (int m = 1; m < 64; m <<= 1) ls += __shfl_xor(ls, m);
        if ((t & 63) == 0) redS[t >> 6] = ls;
        __syncthreads();
        tau = (redS[0] + redS[1] + redS[2] + redS[3] - 1.f) / (float)cnt;
        float kprev = (float)cnt;
        for (int it = 0; it < 64; it++) {
            float s = 0.f, k = 0.f;
            for (int i = t; i < cnt; i += 256) {
                float v = zv[i];
                if (v > tau) { s += v; k += 1.f; }
            }
            #pragma unroll
            for (int m = 1; m < 64; m <<= 1) { s += __shfl_xor(s, m); k += __shfl_xor(k, m); }
            __syncthreads();
            if ((t & 63) == 0) { redS[t >> 6] = s; redK[t >> 6] = k; }
            __syncthreads();
            float S_ = redS[0] + redS[1] + redS[2] + redS[3];
            float K_ = redK[0] + redK[1] + redK[2] + redK[3];
            if (K_ == kprev || K_ < 0.5f) break;
            kprev = K_;
            tau = (S_ - 1.f) / K_;
        }
        int d = t & 127, half = t >> 7;
        float acc = 0.f;
        for (int i = half; i < cnt; i += 2) {
            float w = zv[i] - tau;
            if (w > 0.f) acc = fmaf(w, new_mem[(size_t)zn[i] * 128 + d], acc);
        }
        part[t] = acc;
        __syncthreads();
        if (t < 128) c_mem[c * 128 + t] = part[t] + part[t + 128];
    } else {
        const float* z = simT + (size_t)c * N_NODES;
        float ls = 0.f;
        for (int n = t; n < N_NODES; n += 256) ls += z[n];
        #pragma unroll
        for (int m = 1; m < 64; m <<= 1) ls += __shfl_xor(ls, m);
        if ((t & 63) == 0) redS[t >> 6] = ls;
        __syncthreads();
        tau = (redS[0] + redS[1] + redS[2] + redS[3] - 1.f) / (float)N_NODES;
        float kprev = -1.f;
        for (int it = 0; it < 64; it++) {
            float s = 0.f, k = 0.f;
            for (int n = t; n < N_NODES; n += 256) {
                float v = z[n];
                if (v > tau) { s += v; k += 1.f; }
            }
            #pragma unroll
            for (int m = 1; m < 64; m <<= 1) { s += __shfl_xor(s, m); k += __shfl_xor(k, m); }
            __syncthreads();
            if ((t & 63) == 0) { redS[t >> 6] = s; redK[t >> 6] = k; }
            __syncthreads();
            float S_ = redS[0] + redS[1] + redS[2] + redS[3];
            float K_ = redK[0] + redK[1] + redK[2] + redK[3];
            if (K_ == kprev || K_ < 0.5f) break;
            kprev = K_;
            tau = (S_ - 1.f) / K_;
        }
        int d = t & 127, half = t >> 7;
        float acc = 0.f;
        for (int n = half; n < N_NODES; n += 2) {
            float w = z[n] - tau;
            if (w > 0.f) acc = fmaf(w, new_mem[(size_t)n * 128 + d], acc);
        }
        part[t] = acc;
        __syncthreads();
        if (t < 128) c_mem[c * 128 + t] = part[t] + part[t + 128];
    }
}

// ---------------- node sparsemax + community mix -> emb (32 nodes/block, 512 threads) ----------------
__global__ __launch_bounds__(512) void k_emb(
        const float* __restrict__ simT, const float* __restrict__ c_mem,
        float* __restrict__ out) {
    __shared__ float zb[32 * 257];
    int t = threadIdx.x;
    int n0 = blockIdx.x * 32;
    #pragma unroll
    for (int r = 0; r < 16; r++) {
        int n_l = t & 31, c = r * 16 + (t >> 5);
        zb[n_l * 257 + c] = simT[(size_t)c * N_NODES + (n0 + n_l)];
    }
    __syncthreads();
    int n_l = t >> 4, g = t & 15;
    const float* zr = zb + n_l * 257;
    float s = 0.f;
    #pragma unroll
    for (int j = 0; j < 16; j++) s += zr[g + 16 * j];
    #pragma unroll
    for (int m = 1; m < 16; m <<= 1) s += __shfl_xor(s, m);
    float tau = (s - 1.f) / 256.f;
    float kprev = -1.f;
    for (int it = 0; it < 40; it++) {
        float ls = 0.f, lk = 0.f;
        #pragma unroll
        for (int j = 0; j < 16; j++) {
            float v = zr[g + 16 * j];
            if (v > tau) { ls += v; lk += 1.f; }
        }
        #pragma unroll
        for (int m = 1; m < 16; m <<= 1) { ls += __shfl_xor(ls, m); lk += __shfl_xor(lk, m); }
        if (lk == kprev) break;
        kprev = lk;
        tau = (ls - 1.f) / lk;
    }
    float acc[8];
    #pragma unroll
    for (int j = 0; j < 8; j++) acc[j] = 0.f;
    for (int c = 0; c < 256; c++) {
        float m = zr[c] - tau;
        if (m > 0.f) {
            const float* cm = c_mem + c * 128 + g * 8;
            #pragma unroll
            for (int j = 0; j < 8; j++) acc[j] = fmaf(m, cm[j], acc[j]);
        }
    }
    float* op = out + (size_t)(n0 + n_l) * 128 + g * 8;
    #pragma unroll
    for (int j = 0; j < 8; j++) op[j] += acc[j];
}

extern "C" void kernel_launch(void* const* d_in, const int* in_sizes, int n_in,
                              void* d_out, int out_size, void* d_ws, size_t ws_size,
                              hipStream_t stream) {
    const float* node_memory   = (const float*)d_in[0];
    const float* last_update   = (const float*)d_in[1];
    const float* node_features = (const float*)d_in[2];
    const float* event_feat    = (const float*)d_in[3];
    const float* t_arr         = (const float*)d_in[4];
    const int*   src           = (const int*)d_in[5];
    const int*   dst           = (const int*)d_in[6];
    const float* time_w        = (const float*)d_in[7];
    const float* time_b        = (const float*)d_in[8];
    const float* W_ih          = (const float*)d_in[9];
    const float* b_ih          = (const float*)d_in[10];
    const float* W_hh          = (const float*)d_in[11];
    const float* b_hh          = (const float*)d_in[12];
    const float* proj_W        = (const float*)d_in[13];
    const float* proj_b        = (const float*)d_in[14];
    const float* centroids     = (const float*)d_in[15];

    float* ws     = (float*)d_ws;
    float* S      = ws;                               // N*384 floats; reused as simT
    float* simT   = ws;
    float* cnt    = ws + (size_t)N_NODES * 384;       // N
    short* Wbf    = (short*)(cnt + N_NODES);          // 512*512 bf16 (131072 floats)
    float* bcat   = (float*)(Wbf + 512 * 512);        // 512
    float* c_mem  = bcat + 512;                       // 256*128
    float* gcnt   = c_mem + 256 * 128;                // 256*33
    float* thresh = gcnt + 256 * (NLAD + 1);          // 256
    int*   ccount = (int*)(thresh + 256);             // 256
    float2* clist = (float2*)(thresh + 512);          // 256*CAP float2
    short* cenf_hi = (short*)(clist + 256 * CAP);     // 32768 shorts
    short* cenf_lo = cenf_hi + 256 * 128;             // 32768 shorts
    short* pw_hi   = cenf_lo + 256 * 128;             // 16384 shorts
    short* pw_lo   = pw_hi + 128 * 128;               // 16384 shorts
    float* out    = (float*)d_out;

    hipMemsetAsync(S, 0, ((size_t)N_NODES * 384 + N_NODES) * sizeof(float), stream);
    hipMemsetAsync(gcnt, 0, (256 * (NLAD + 1) + 512) * sizeof(float), stream);
    k_build<<<1024, 256, 0, stream>>>(W_ih, b_ih, W_hh, b_hh, Wbf, bcat);
    k_cen<<<256, 128, 0, stream>>>(centroids, cenf_hi, cenf_lo);
    k_packW<<<64, 256, 0, stream>>>(proj_W, pw_hi, pw_lo);
    k_scatter<<<(2 * N_EV) / 4, 256, 0, stream>>>(node_memory, last_update, event_feat,
                                                  t_arr, src, dst, time_w, time_b, S, cnt);
    k_gru<<<N_NODES / 32, 512, 0, stream>>>(node_memory, S, cnt, Wbf, bcat, out);
    k_sim<<<(N_NODES + 63) / 64, 256, 0, stream>>>(out, node_features, pw_hi, pw_lo,
                                                   proj_b, cenf_hi, cenf_lo, simT);
    k_hist<<<1024, 256, 0, stream>>>(simT, gcnt);
    k_tau0<<<1, 256, 0, stream>>>(gcnt, thresh);
    k_gather<<<1024, 256, 0, stream>>>(simT, thresh, ccount, clist);
    k_csolve<<<256, 256, 0, stream>>>(simT, out, ccount, clist, c_mem);
    k_emb<<<N_NODES / 32, 512, 0, stream>>>(simT, c_mem, out);
}

// Round 7
// 902.204 us; speedup vs baseline: 8.2697x; 8.2697x over previous
//
#include <hip/hip_runtime.h>
#include <math.h>

#define N_NODES 100000
#define N_EV    50000
#define NF4     25000   // N_NODES/4
#define CAP     1024    // candidate list capacity per community

typedef __attribute__((ext_vector_type(8))) short short8;
typedef __attribute__((ext_vector_type(4))) float f32x4;

static __device__ __forceinline__ short f2bf(float f) {
    union { float f; unsigned u; } v; v.f = f;
    unsigned r = (v.u + 0x7FFFu + ((v.u >> 16) & 1u)) >> 16;
    return (short)r;
}
static __device__ __forceinline__ float bf2f(short h) {
    union { unsigned u; float f; } v; v.u = ((unsigned)(unsigned short)h) << 16;
    return v.f;
}

// ---------------- build GRU weight matrix in MFMA-fragment order (bf16) ----------------
__global__ void k_build(const float* __restrict__ W_ih, const float* __restrict__ b_ih,
                        const float* __restrict__ W_hh, const float* __restrict__ b_hh,
                        short* __restrict__ Wbf, float* __restrict__ bcat) {
    int idx = blockIdx.x * 256 + threadIdx.x;   // 512*512 = 262144
    int j = idx & 7, lane = (idx >> 3) & 63, sub = idx >> 9;
    int ks = sub & 15, NB = sub >> 4;
    int k = ks * 32 + ((lane >> 4) & 3) * 8 + j;
    int o = NB * 16 + (lane & 15);
    int g = o >> 7, d = o & 127;
    float v;
    if (g == 0)      v = W_ih[d * 512 + k] + (k < 128 ? W_hh[d * 128 + k] : 0.f);
    else if (g == 1) v = W_ih[(128 + d) * 512 + k] + (k < 128 ? W_hh[(128 + d) * 128 + k] : 0.f);
    else if (g == 2) v = W_ih[(256 + d) * 512 + k];
    else             v = (k < 128 ? W_hh[(256 + d) * 128 + k] : 0.f);
    Wbf[idx] = f2bf(v);
    if (idx < 512) {
        int gg = idx >> 7, dd = idx & 127;
        float b;
        if (gg == 0)      b = b_ih[dd] + b_hh[dd];
        else if (gg == 1) b = b_ih[128 + dd] + b_hh[128 + dd];
        else if (gg == 2) b = b_ih[256 + dd];
        else              b = b_hh[256 + dd];
        bcat[idx] = b;
    }
}

// ---------------- normalize centroids + pack hi/lo A-fragments ----------------
__global__ void k_cen(const float* __restrict__ centroids,
                      short* __restrict__ cenf_hi, short* __restrict__ cenf_lo) {
    int c = blockIdx.x, t = threadIdx.x;  // 128 threads
    float v = centroids[c * 128 + t];
    float ss = v * v;
    #pragma unroll
    for (int m = 1; m < 64; m <<= 1) ss += __shfl_xor(ss, m);
    __shared__ float tmp[2];
    if ((t & 63) == 0) tmp[t >> 6] = ss;
    __syncthreads();
    float tot = tmp[0] + tmp[1];
    float nv = v / (sqrtf(tot) + 1e-8f);
    short hi = f2bf(nv);
    short lo = f2bf(nv - bf2f(hi));
    int ct = c >> 4, c_l = c & 15, kstep = t >> 5, kj = t & 31;
    int lane = c_l + 16 * (kj >> 3), j = kj & 7;
    int fidx = ((ct * 4 + kstep) * 64 + lane) * 8 + j;
    cenf_hi[fidx] = hi;
    cenf_lo[fidx] = lo;
}

// ---------------- pack proj_W hi/lo B-fragments ----------------
__global__ void k_packW(const float* __restrict__ proj_W,
                        short* __restrict__ pw_hi, short* __restrict__ pw_lo) {
    int idx = blockIdx.x * 256 + threadIdx.x;   // 16384
    int k = idx >> 7, p = idx & 127;
    float v = proj_W[k * 128 + p];
    short hi = f2bf(v);
    short lo = f2bf(v - bf2f(hi));
    int pt = p >> 4, p_l = p & 15, kstep = k >> 5, kj = k & 31;
    int lane = p_l + 16 * (kj >> 3), j = kj & 7;
    int fidx = ((pt * 4 + kstep) * 64 + lane) * 8 + j;
    pw_hi[fidx] = hi;
    pw_lo[fidx] = lo;
}

// ---------------- event scatter ----------------
__global__ __launch_bounds__(256) void k_scatter(
        const float* __restrict__ node_memory, const float* __restrict__ last_update,
        const float* __restrict__ event_feat, const float* __restrict__ t_arr,
        const int* __restrict__ src, const int* __restrict__ dst,
        const float* __restrict__ time_w, const float* __restrict__ time_b,
        float* __restrict__ S, float* __restrict__ cnt) {
    int e = blockIdx.x * 4 + (threadIdx.x >> 6);   // one wave per event, e in [0, 2E)
    int l = threadIdx.x & 63;
    int eb  = e < N_EV ? e : e - N_EV;
    int idx = e < N_EV ? src[e] : dst[eb];
    int oth = e < N_EV ? dst[e] : src[eb];
    float tt = t_arr[eb];
    float dt = tt - last_update[idx];
    float* Sd = S + (size_t)idx * 384;
    const float* om = node_memory + (size_t)oth * 128;
    const float* ef = event_feat + (size_t)eb * 128;
    #pragma unroll
    for (int h = 0; h < 2; h++) {
        int d = l + h * 64;
        atomicAdd(&Sd[d], om[d]);
        atomicAdd(&Sd[128 + d], ef[d]);
        atomicAdd(&Sd[256 + d], cosf(fmaf(dt, time_w[d], time_b[d])));
    }
    if (l == 0) atomicAdd(&cnt[idx], 1.0f);
}

// ---------------- fused GRU via MFMA bf16 (32 nodes/block, 512 threads, 8 waves) ----------------
__global__ __launch_bounds__(512, 4) void k_gru(
        const float* __restrict__ node_memory, const float* __restrict__ S,
        const float* __restrict__ cnt, const short* __restrict__ Wbf,
        const float* __restrict__ bcat, float* __restrict__ new_mem) {
    __shared__ __align__(16) char ldsraw[65536];
    short* Ab  = (short*)ldsraw;          // 32 KiB: 32 nodes x 512 k bf16 (frag order)
    float* epi = (float*)ldsraw;          // 64 KiB: [4 gates][32 rows][128 d] (after K-loop)
    int t = threadIdx.x;
    int n0 = blockIdx.x * 32;

    #pragma unroll
    for (int pass = 0; pass < 4; pass++) {
        int m = t >> 4;                       // 0..31
        int k0 = (t & 15) * 8 + pass * 128;   // 0..504
        float vals[8];
        if (pass == 0) {
            const float4* p = (const float4*)&node_memory[(size_t)(n0 + m) * 128 + k0];
            float4 x = p[0], y = p[1];
            vals[0]=x.x; vals[1]=x.y; vals[2]=x.z; vals[3]=x.w;
            vals[4]=y.x; vals[5]=y.y; vals[6]=y.z; vals[7]=y.w;
        } else {
            float inv = 1.f / fmaxf(cnt[n0 + m], 1.f);
            const float4* p = (const float4*)&S[(size_t)(n0 + m) * 384 + (k0 - 128)];
            float4 x = p[0], y = p[1];
            vals[0]=x.x*inv; vals[1]=x.y*inv; vals[2]=x.z*inv; vals[3]=x.w*inv;
            vals[4]=y.x*inv; vals[5]=y.y*inv; vals[6]=y.z*inv; vals[7]=y.w*inv;
        }
        int mb = m >> 4, ks = k0 >> 5;
        int lane = ((k0 >> 3) & 3) * 16 + (m & 15);
        int g = (mb * 16 + ks) * 64 + lane;
        g ^= ((g >> 4) & 7);
        short8 sv;
        #pragma unroll
        for (int j = 0; j < 8; j++) sv[j] = f2bf(vals[j]);
        *(short8*)&Ab[g * 8] = sv;
    }
    __syncthreads();

    int w = t >> 6, l = t & 63;
    int cg = w & 3, kh = w >> 2;
    f32x4 acc[2][8];
    #pragma unroll
    for (int mb = 0; mb < 2; mb++)
        #pragma unroll
        for (int nb = 0; nb < 8; nb++) acc[mb][nb] = (f32x4){0.f, 0.f, 0.f, 0.f};

    const short8* Bp = (const short8*)Wbf;
    #pragma unroll 2
    for (int kk = 0; kk < 8; kk++) {
        int ks = kh * 8 + kk;
        short8 bfr[8];
        #pragma unroll
        for (int nb = 0; nb < 8; nb++)
            bfr[nb] = Bp[(((cg * 8 + nb) * 16 + ks) * 64) + l];
        short8 afr[2];
        #pragma unroll
        for (int mb = 0; mb < 2; mb++) {
            int g = (mb * 16 + ks) * 64 + l;
            g ^= ((g >> 4) & 7);
            afr[mb] = *(const short8*)&Ab[g * 8];
        }
        #pragma unroll
        for (int mb = 0; mb < 2; mb++)
            #pragma unroll
            for (int nb = 0; nb < 8; nb++)
                acc[mb][nb] = __builtin_amdgcn_mfma_f32_16x16x32_bf16(
                    afr[mb], bfr[nb], acc[mb][nb], 0, 0, 0);
    }
    __syncthreads();   // A dead -> epi reuse

    if (kh == 0) {
        #pragma unroll
        for (int mb = 0; mb < 2; mb++)
            #pragma unroll
            for (int nb = 0; nb < 8; nb++)
                #pragma unroll
                for (int r = 0; r < 4; r++) {
                    int row = mb * 16 + (l >> 4) * 4 + r;
                    int d = nb * 16 + (l & 15);
                    epi[(cg * 32 + row) * 128 + d] = acc[mb][nb][r];
                }
    }
    __syncthreads();
    if (kh == 1) {
        #pragma unroll
        for (int mb = 0; mb < 2; mb++)
            #pragma unroll
            for (int nb = 0; nb < 8; nb++)
                #pragma unroll
                for (int r = 0; r < 4; r++) {
                    int row = mb * 16 + (l >> 4) * 4 + r;
                    int d = nb * 16 + (l & 15);
                    epi[(cg * 32 + row) * 128 + d] += acc[mb][nb][r];
                }
    }
    __syncthreads();

    int d = t & 127;
    float br = bcat[d], bz = bcat[128 + d], bn = bcat[256 + d], bh = bcat[384 + d];
    #pragma unroll
    for (int i = 0; i < 8; i++) {
        int row = (t >> 7) * 8 + i;
        int n = n0 + row;
        float c = cnt[n];
        float h = node_memory[(size_t)n * 128 + d];
        float rs = epi[(0 * 32 + row) * 128 + d] + br;
        float zs = epi[(1 * 32 + row) * 128 + d] + bz;
        float gn = epi[(2 * 32 + row) * 128 + d] + bn;
        float gh = epi[(3 * 32 + row) * 128 + d] + bh;
        float r_ = 1.f / (1.f + expf(-rs));
        float z_ = 1.f / (1.f + expf(-zs));
        float nn = tanhf(gn + r_ * gh);
        float nm = (1.f - z_) * nn + z_ * h;
        new_mem[(size_t)n * 128 + d] = (c > 0.f) ? nm : h;
    }
}

// ---------------- k_sim: feat -> proj -> normalize -> sim via split-bf16 MFMA ----------------
__global__ __launch_bounds__(256, 2) void k_sim(
        const float* __restrict__ new_mem, const float* __restrict__ node_features,
        const short* __restrict__ pw_hi, const short* __restrict__ pw_lo,
        const float* __restrict__ proj_b,
        const short* __restrict__ cenf_hi, const short* __restrict__ cenf_lo,
        float* __restrict__ simT) {
    __shared__ __align__(16) float feat[64 * 128];   // 32 KB, XOR-swizzled 16B granules
    __shared__ __align__(16) short pfh[64 * 128];    // 16 KB
    __shared__ __align__(16) short pfl[64 * 128];    // 16 KB
    int t = threadIdx.x;
    int n0 = blockIdx.x * 64;

    #pragma unroll
    for (int r = 0; r < 8; r++) {
        int idx = r * 256 + t;            // granule 0..2047
        int node = idx >> 5, gk = idx & 31;
        float4 v = make_float4(0.f, 0.f, 0.f, 0.f);
        int n = n0 + node;
        if (n < N_NODES) {
            float4 a = *(const float4*)&new_mem[(size_t)n * 128 + gk * 4];
            float4 b = *(const float4*)&node_features[(size_t)n * 128 + gk * 4];
            v = make_float4(a.x + b.x, a.y + b.y, a.z + b.z, a.w + b.w);
        }
        int gs = gk ^ (node & 7);
        *(float4*)&feat[(node * 32 + gs) * 4] = v;
    }
    __syncthreads();

    int w = t >> 6, l = t & 63;
    int lm = l & 15, lk = l >> 4;

    f32x4 pacc[8];
    #pragma unroll
    for (int nb = 0; nb < 8; nb++) pacc[nb] = (f32x4){0.f, 0.f, 0.f, 0.f};
    #pragma unroll
    for (int ks = 0; ks < 4; ks++) {
        int node = w * 16 + lm;
        int gk0 = ks * 8 + lk * 2;
        float4 a0 = *(const float4*)&feat[(node * 32 + (gk0 ^ (node & 7))) * 4];
        float4 a1 = *(const float4*)&feat[(node * 32 + ((gk0 + 1) ^ (node & 7))) * 4];
        float av[8] = {a0.x, a0.y, a0.z, a0.w, a1.x, a1.y, a1.z, a1.w};
        short8 Ah, Al;
        #pragma unroll
        for (int j = 0; j < 8; j++) {
            short h = f2bf(av[j]);
            Ah[j] = h;
            Al[j] = f2bf(av[j] - bf2f(h));
        }
        #pragma unroll
        for (int nb = 0; nb < 8; nb++) {
            int fidx = ((nb * 4 + ks) * 64 + l) * 8;
            short8 Bh = *(const short8*)&pw_hi[fidx];
            short8 Bl = *(const short8*)&pw_lo[fidx];
            pacc[nb] = __builtin_amdgcn_mfma_f32_16x16x32_bf16(Ah, Bh, pacc[nb], 0, 0, 0);
            pacc[nb] = __builtin_amdgcn_mfma_f32_16x16x32_bf16(Ah, Bl, pacc[nb], 0, 0, 0);
            pacc[nb] = __builtin_amdgcn_mfma_f32_16x16x32_bf16(Al, Bh, pacc[nb], 0, 0, 0);
        }
    }
    float ssq[4] = {0.f, 0.f, 0.f, 0.f};
    #pragma unroll
    for (int nb = 0; nb < 8; nb++) {
        float pb = proj_b[nb * 16 + lm];
        #pragma unroll
        for (int r = 0; r < 4; r++) {
            pacc[nb][r] += pb;
            ssq[r] = fmaf(pacc[nb][r], pacc[nb][r], ssq[r]);
        }
    }
    #pragma unroll
    for (int m = 1; m < 16; m <<= 1)
        #pragma unroll
        for (int r = 0; r < 4; r++) ssq[r] += __shfl_xor(ssq[r], m);
    float inv[4];
    #pragma unroll
    for (int r = 0; r < 4; r++) inv[r] = 1.f / (sqrtf(ssq[r]) + 1e-8f);
    #pragma unroll
    for (int nb = 0; nb < 8; nb++)
        #pragma unroll
        for (int r = 0; r < 4; r++) {
            float v = pacc[nb][r] * inv[r];
            short h = f2bf(v);
            short lo2 = f2bf(v - bf2f(h));
            int node = w * 16 + lk * 4 + r;
            int p = nb * 16 + lm;
            int g = node * 16 + (((p >> 3)) ^ (node & 7));
            int si = g * 8 + (p & 7);
            pfh[si] = h;
            pfl[si] = lo2;
        }
    __syncthreads();

    f32x4 sacc[4][4];
    #pragma unroll
    for (int ct = 0; ct < 4; ct++)
        #pragma unroll
        for (int mt = 0; mt < 4; mt++) sacc[ct][mt] = (f32x4){0.f, 0.f, 0.f, 0.f};
    #pragma unroll
    for (int ks = 0; ks < 4; ks++) {
        short8 Bh[4], Bl[4];
        #pragma unroll
        for (int mt = 0; mt < 4; mt++) {
            int node = mt * 16 + lm;
            int g = node * 16 + ((ks * 4 + lk) ^ (node & 7));
            Bh[mt] = *(const short8*)&pfh[g * 8];
            Bl[mt] = *(const short8*)&pfl[g * 8];
        }
        #pragma unroll
        for (int ct = 0; ct < 4; ct++) {
            int ctg = w * 4 + ct;
            int fidx = ((ctg * 4 + ks) * 64 + l) * 8;
            short8 Ah = *(const short8*)&cenf_hi[fidx];
            short8 Al = *(const short8*)&cenf_lo[fidx];
            #pragma unroll
            for (int mt = 0; mt < 4; mt++) {
                sacc[ct][mt] = __builtin_amdgcn_mfma_f32_16x16x32_bf16(Ah, Bh[mt], sacc[ct][mt], 0, 0, 0);
                sacc[ct][mt] = __builtin_amdgcn_mfma_f32_16x16x32_bf16(Ah, Bl[mt], sacc[ct][mt], 0, 0, 0);
                sacc[ct][mt] = __builtin_amdgcn_mfma_f32_16x16x32_bf16(Al, Bh[mt], sacc[ct][mt], 0, 0, 0);
            }
        }
    }
    #pragma unroll
    for (int ct = 0; ct < 4; ct++) {
        int cbase = (w * 4 + ct) * 16 + lk * 4;
        #pragma unroll
        for (int r = 0; r < 4; r++) {
            size_t rowoff = (size_t)(cbase + r) * N_NODES;
            #pragma unroll
            for (int mt = 0; mt < 4; mt++) {
                int n = n0 + mt * 16 + lm;
                if (n < N_NODES) simT[rowoff + n] = sacc[ct][mt][r];
            }
        }
    }
}

// ---------------- pass A: 256-bin histogram, 16x sub-histogram replication ----------------
__global__ __launch_bounds__(256) void k_hist(const float* __restrict__ simT,
                                              float* __restrict__ ghist) {
    int cid = blockIdx.x >> 2, slice = blockIdx.x & 3;
    int t = threadIdx.x;
    __shared__ float hc[256 * 16];   // 16 KB: [bin][sub]
    __shared__ float hs[256 * 16];   // 16 KB
    #pragma unroll
    for (int i = 0; i < 16; i++) { hc[i * 256 + t] = 0.f; hs[i * 256 + t] = 0.f; }
    __syncthreads();
    int sub = t & 15;
    const float4* z4 = (const float4*)(simT + (size_t)cid * N_NODES);
    int end = slice * 6250 + 6250;
    for (int i = slice * 6250 + t; i < end; i += 256) {
        float4 a = z4[i];
        #define PUTH(v) { int b = (int)fmaf((v), 128.f, 128.f); b = b < 0 ? 0 : (b > 255 ? 255 : b); \
                          atomicAdd(&hc[b * 16 + sub], 1.f); atomicAdd(&hs[b * 16 + sub], (v)); }
        PUTH(a.x) PUTH(a.y) PUTH(a.z) PUTH(a.w)
        #undef PUTH
    }
    __syncthreads();
    float c = 0.f, s = 0.f;
    #pragma unroll
    for (int j = 0; j < 16; j++) { c += hc[t * 16 + j]; s += hs[t * 16 + j]; }
    atomicAdd(&ghist[cid * 512 + t], c);
    atomicAdd(&ghist[cid * 512 + 256 + t], s);
}

// ---------------- pass B: binned Michelot on suffix sums -> thresh <= tau* ----------------
__global__ void k_tau0(const float* __restrict__ ghist, float* __restrict__ thresh) {
    int c = blockIdx.x, t = threadIdx.x;  // 256 threads
    __shared__ float bc[256], bs[256], ck[256], cs[256];
    bc[t] = ghist[c * 512 + t];
    bs[t] = ghist[c * 512 + 256 + t];
    __syncthreads();
    if (t == 0) {
        float ak = 0.f, as = 0.f;
        for (int b = 255; b >= 0; b--) { ak += bc[b]; as += bs[b]; ck[b] = ak; cs[b] = as; }
        float tau = (cs[0] - 1.f) / (float)N_NODES;   // superset lemma: <= tau*
        float best = tau;
        int bprev = -1;
        for (int it = 0; it < 48; it++) {
            int b = (int)fmaf(tau, 128.f, 128.f);
            b = b < 0 ? 0 : (b > 255 ? 255 : b);
            if (b == bprev) break;
            bprev = b;
            float K = ck[b];
            if (K < 0.5f) break;
            tau = (cs[b] - 1.f) / K;                  // still <= tau*
            if (tau > best) best = tau;
        }
        thresh[c] = best - 1e-5f;                     // margin for fp rounding
    }
}

// ---------------- pass C: gather candidates z > thresh ----------------
__global__ __launch_bounds__(256) void k_gather(const float* __restrict__ simT,
                                                const float* __restrict__ thresh,
                                                int* __restrict__ ccount,
                                                float2* __restrict__ clist) {
    int cid = blockIdx.x >> 2, slice = blockIdx.x & 3;
    float th = thresh[cid];
    const float4* z4 = (const float4*)(simT + (size_t)cid * N_NODES);
    int t = threadIdx.x;
    int end = slice * 6250 + 6250;
    for (int i = slice * 6250 + t; i < end; i += 256) {
        float4 a = z4[i];
        int nb = i * 4;
        #define GATH(v, j) if ((v) > th) { int p = atomicAdd(&ccount[cid], 1); \
            if (p < CAP) clist[(size_t)cid * CAP + p] = make_float2((v), __int_as_float(nb + (j))); }
        GATH(a.x, 0) GATH(a.y, 1) GATH(a.z, 2) GATH(a.w, 3)
        #undef GATH
    }
}

// ---------------- pass D: exact Michelot on candidates + c_mem accumulation ----------------
__global__ __launch_bounds__(256) void k_csolve(
        const float* __restrict__ simT, const float* __restrict__ new_mem,
        const int* __restrict__ ccount, const float2* __restrict__ clist,
        float* __restrict__ c_mem) {
    int c = blockIdx.x, t = threadIdx.x;  // 256 threads
    __shared__ float zv[CAP];
    __shared__ int   zn[CAP];
    __shared__ float redS[4], redK[4], part[256];
    int raw = ccount[c];
    if (raw == 0) {
        if (t < 128) c_mem[c * 128 + t] = 0.f;
        return;
    }
    float tau;
    if (raw <= CAP) {
        int cnt = raw;
        for (int i = t; i < cnt; i += 256) {
            float2 e = clist[(size_t)c * CAP + i];
            zv[i] = e.x; zn[i] = __float_as_int(e.y);
        }
        __syncthreads();
        float ls = 0.f;
        for (int i = t; i < cnt; i += 256) ls += zv[i];
        #pragma unroll
        for (int m = 1; m < 64; m <<= 1) ls += __shfl_xor(ls, m);
        if ((t & 63) == 0) redS[t >> 6] = ls;
        __syncthreads();
        tau = (redS[0] + redS[1] + redS[2] + redS[3] - 1.f) / (float)cnt;
        float kprev = (float)cnt;
        for (int it = 0; it < 64; it++) {
            float s = 0.f, k = 0.f;
            for (int i = t; i < cnt; i += 256) {
                float v = zv[i];
                if (v > tau) { s += v; k += 1.f; }
            }
            #pragma unroll
            for (int m = 1; m < 64; m <<= 1) { s += __shfl_xor(s, m); k += __shfl_xor(k, m); }
            __syncthreads();
            if ((t & 63) == 0) { redS[t >> 6] = s; redK[t >> 6] = k; }
            __syncthreads();
            float S_ = redS[0] + redS[1] + redS[2] + redS[3];
            float K_ = redK[0] + redK[1] + redK[2] + redK[3];
            if (K_ == kprev || K_ < 0.5f) break;
            kprev = K_;
            tau = (S_ - 1.f) / K_;
        }
        int d = t & 127, half = t >> 7;
        float acc = 0.f;
        for (int i = half; i < cnt; i += 2) {
            float w = zv[i] - tau;
            if (w > 0.f) acc = fmaf(w, new_mem[(size_t)zn[i] * 128 + d], acc);
        }
        part[t] = acc;
        __syncthreads();
        if (t < 128) c_mem[c * 128 + t] = part[t] + part[t + 128];
    } else {
        const float* z = simT + (size_t)c * N_NODES;
        float ls = 0.f;
        for (int n = t; n < N_NODES; n += 256) ls += z[n];
        #pragma unroll
        for (int m = 1; m < 64; m <<= 1) ls += __shfl_xor(ls, m);
        if ((t & 63) == 0) redS[t >> 6] = ls;
        __syncthreads();
        tau = (redS[0] + redS[1] + redS[2] + redS[3] - 1.f) / (float)N_NODES;
        float kprev = -1.f;
        for (int it = 0; it < 64; it++) {
            float s = 0.f, k = 0.f;
            for (int n = t; n < N_NODES; n += 256) {
                float v = z[n];
                if (v > tau) { s += v; k += 1.f; }
            }
            #pragma unroll
            for (int m = 1; m < 64; m <<= 1) { s += __shfl_xor(s, m); k += __shfl_xor(k, m); }
            __syncthreads();
            if ((t & 63) == 0) { redS[t >> 6] = s; redK[t >> 6] = k; }
            __syncthreads();
            float S_ = redS[0] + redS[1] + redS[2] + redS[3];
            float K_ = redK[0] + redK[1] + redK[2] + redK[3];
            if (K_ == kprev || K_ < 0.5f) break;
            kprev = K_;
            tau = (S_ - 1.f) / K_;
        }
        int d = t & 127, half = t >> 7;
        float acc = 0.f;
        for (int n = half; n < N_NODES; n += 2) {
            float w = z[n] - tau;
            if (w > 0.f) acc = fmaf(w, new_mem[(size_t)n * 128 + d], acc);
        }
        part[t] = acc;
        __syncthreads();
        if (t < 128) c_mem[c * 128 + t] = part[t] + part[t + 128];
    }
}

// ---------------- node sparsemax + community mix -> emb (32 nodes/block, 512 threads) ----------------
__global__ __launch_bounds__(512) void k_emb(
        const float* __restrict__ simT, const float* __restrict__ c_mem,
        float* __restrict__ out) {
    __shared__ float zb[32 * 257];
    int t = threadIdx.x;
    int n0 = blockIdx.x * 32;
    #pragma unroll
    for (int r = 0; r < 16; r++) {
        int n_l = t & 31, c = r * 16 + (t >> 5);
        zb[n_l * 257 + c] = simT[(size_t)c * N_NODES + (n0 + n_l)];
    }
    __syncthreads();
    int n_l = t >> 4, g = t & 15;
    const float* zr = zb + n_l * 257;
    float s = 0.f;
    #pragma unroll
    for (int j = 0; j < 16; j++) s += zr[g + 16 * j];
    #pragma unroll
    for (int m = 1; m < 16; m <<= 1) s += __shfl_xor(s, m);
    float tau = (s - 1.f) / 256.f;
    float kprev = -1.f;
    for (int it = 0; it < 40; it++) {
        float ls = 0.f, lk = 0.f;
        #pragma unroll
        for (int j = 0; j < 16; j++) {
            float v = zr[g + 16 * j];
            if (v > tau) { ls += v; lk += 1.f; }
        }
        #pragma unroll
        for (int m = 1; m < 16; m <<= 1) { ls += __shfl_xor(ls, m); lk += __shfl_xor(lk, m); }
        if (lk == kprev) break;
        kprev = lk;
        tau = (ls - 1.f) / lk;
    }
    float acc[8];
    #pragma unroll
    for (int j = 0; j < 8; j++) acc[j] = 0.f;
    for (int c = 0; c < 256; c++) {
        float m = zr[c] - tau;
        if (m > 0.f) {
            const float* cm = c_mem + c * 128 + g * 8;
            #pragma unroll
            for (int j = 0; j < 8; j++) acc[j] = fmaf(m, cm[j], acc[j]);
        }
    }
    float* op = out + (size_t)(n0 + n_l) * 128 + g * 8;
    #pragma unroll
    for (int j = 0; j < 8; j++) op[j] += acc[j];
}

extern "C" void kernel_launch(void* const* d_in, const int* in_sizes, int n_in,
                              void* d_out, int out_size, void* d_ws, size_t ws_size,
                              hipStream_t stream) {
    const float* node_memory   = (const float*)d_in[0];
    const float* last_update   = (const float*)d_in[1];
    const float* node_features = (const float*)d_in[2];
    const float* event_feat    = (const float*)d_in[3];
    const float* t_arr         = (const float*)d_in[4];
    const int*   src           = (const int*)d_in[5];
    const int*   dst           = (const int*)d_in[6];
    const float* time_w        = (const float*)d_in[7];
    const float* time_b        = (const float*)d_in[8];
    const float* W_ih          = (const float*)d_in[9];
    const float* b_ih          = (const float*)d_in[10];
    const float* W_hh          = (const float*)d_in[11];
    const float* b_hh          = (const float*)d_in[12];
    const float* proj_W        = (const float*)d_in[13];
    const float* proj_b        = (const float*)d_in[14];
    const float* centroids     = (const float*)d_in[15];

    float* ws     = (float*)d_ws;
    float* S      = ws;                               // N*384 floats; reused as simT
    float* simT   = ws;
    float* cnt    = ws + (size_t)N_NODES * 384;       // N
    short* Wbf    = (short*)(cnt + N_NODES);          // 512*512 bf16 (131072 floats)
    float* bcat   = (float*)(Wbf + 512 * 512);        // 512
    float* c_mem  = bcat + 512;                       // 256*128
    float* ghist  = c_mem + 256 * 128;                // 256*512
    float* thresh = ghist + 256 * 512;                // 256
    int*   ccount = (int*)(thresh + 256);             // 256
    float2* clist = (float2*)(thresh + 512);          // 256*CAP float2
    short* cenf_hi = (short*)(clist + 256 * CAP);     // 32768 shorts
    short* cenf_lo = cenf_hi + 256 * 128;             // 32768 shorts
    short* pw_hi   = cenf_lo + 256 * 128;             // 16384 shorts
    short* pw_lo   = pw_hi + 128 * 128;               // 16384 shorts
    float* out    = (float*)d_out;

    hipMemsetAsync(S, 0, ((size_t)N_NODES * 384 + N_NODES) * sizeof(float), stream);
    hipMemsetAsync(ghist, 0, (256 * 512 + 512) * sizeof(float), stream);
    k_build<<<1024, 256, 0, stream>>>(W_ih, b_ih, W_hh, b_hh, Wbf, bcat);
    k_cen<<<256, 128, 0, stream>>>(centroids, cenf_hi, cenf_lo);
    k_packW<<<64, 256, 0, stream>>>(proj_W, pw_hi, pw_lo);
    k_scatter<<<(2 * N_EV) / 4, 256, 0, stream>>>(node_memory, last_update, event_feat,
                                                  t_arr, src, dst, time_w, time_b, S, cnt);
    k_gru<<<N_NODES / 32, 512, 0, stream>>>(node_memory, S, cnt, Wbf, bcat, out);
    k_sim<<<(N_NODES + 63) / 64, 256, 0, stream>>>(out, node_features, pw_hi, pw_lo,
                                                   proj_b, cenf_hi, cenf_lo, simT);
    k_hist<<<1024, 256, 0, stream>>>(simT, ghist);
    k_tau0<<<256, 256, 0, stream>>>(ghist, thresh);
    k_gather<<<1024, 256, 0, stream>>>(simT, thresh, ccount, clist);
    k_csolve<<<256, 256, 0, stream>>>(simT, out, ccount, clist, c_mem);
    k_emb<<<N_NODES / 32, 512, 0, stream>>>(simT, c_mem, out);
}